// Round 1
// baseline (389.614 us; speedup 1.0000x reference)
//
#include <hip/hip_runtime.h>
#include <cstddef>

#define WIN 11
#define HALO 10
#define NCH 10

typedef float v4f __attribute__((ext_vector_type(4)));

// Normalized 1D Gaussian, sigma=1.5 (constexpr: unrolled taps fold to immediates)
constexpr float Gc[WIN] = {
    0.00102838f, 0.00759876f, 0.03600077f, 0.10936069f, 0.21300554f,
    0.26601173f, 0.21300554f, 0.10936069f, 0.03600077f, 0.00759876f,
    0.00102838f};

constexpr int HPITCH = 33;        // odd pitch: spread banks
constexpr int RS = 42;            // ring slots; B=16 batch: live span 2*16+10 = 42
constexpr int RSZ = RS * HPITCH;  // 1386 v4f = 22176 B -> 7 blocks/CU (was 4)

struct Ptrs {
    const float* p[5];
    const float* t[5];
};

// ---- One-shot pyramid: 64x64 lvl0 tile -> lvl1..4, plus acc zeroing ----
// (~110 MB in ~15us ~= 7 TB/s: at the HBM/L3 roofline — do not touch)
__global__ __launch_bounds__(256) void pool_all(
    const float* __restrict__ P0, const float* __restrict__ T0,
    float* __restrict__ p1, float* __restrict__ t1,
    float* __restrict__ p2, float* __restrict__ t2,
    float* __restrict__ p3, float* __restrict__ t3,
    float* __restrict__ p4, float* __restrict__ t4,
    float* __restrict__ acc) {
    __shared__ float sp2[256], st2[256], sp3[64], st3[64];
    const int tid = threadIdx.x;
    if (blockIdx.x == 0 && tid < 128) acc[tid] = 0.f;

    const int b = blockIdx.x;  // 2560 = 10ch x 16 x 16
    const int bx = b & 15, by = (b >> 4) & 15, ch = b >> 8;
    const int tx = tid & 15, ty = tid >> 4;

    const size_t rbase =
        ((size_t)ch * 1024 + by * 64 + ty * 4) * 1024 + bx * 64 + tx * 4;
    float4 pr[4], tr[4];
#pragma unroll
    for (int r2 = 0; r2 < 4; ++r2) {
        pr[r2] = *(const float4*)(P0 + rbase + (size_t)r2 * 1024);
        tr[r2] = *(const float4*)(T0 + rbase + (size_t)r2 * 1024);
    }
    float p1a = 0.25f * ((pr[0].x + pr[0].y) + (pr[1].x + pr[1].y));
    float p1b = 0.25f * ((pr[0].z + pr[0].w) + (pr[1].z + pr[1].w));
    float p1c = 0.25f * ((pr[2].x + pr[2].y) + (pr[3].x + pr[3].y));
    float p1d = 0.25f * ((pr[2].z + pr[2].w) + (pr[3].z + pr[3].w));
    float t1a = 0.25f * ((tr[0].x + tr[0].y) + (tr[1].x + tr[1].y));
    float t1b = 0.25f * ((tr[0].z + tr[0].w) + (tr[1].z + tr[1].w));
    float t1c = 0.25f * ((tr[2].x + tr[2].y) + (tr[3].x + tr[3].y));
    float t1d = 0.25f * ((tr[2].z + tr[2].w) + (tr[3].z + tr[3].w));
    size_t o1 = ((size_t)ch * 512 + by * 32 + ty * 2) * 512 + bx * 32 + tx * 2;
    *(float2*)(p1 + o1) = make_float2(p1a, p1b);
    *(float2*)(p1 + o1 + 512) = make_float2(p1c, p1d);
    *(float2*)(t1 + o1) = make_float2(t1a, t1b);
    *(float2*)(t1 + o1 + 512) = make_float2(t1c, t1d);
    float p2v = 0.25f * ((p1a + p1b) + (p1c + p1d));
    float t2v = 0.25f * ((t1a + t1b) + (t1c + t1d));
    size_t o2 = ((size_t)ch * 256 + by * 16 + ty) * 256 + bx * 16 + tx;
    p2[o2] = p2v;
    t2[o2] = t2v;
    sp2[tid] = p2v;
    st2[tid] = t2v;
    __syncthreads();
    if (tid < 64) {
        int x3 = tid & 7, y3 = tid >> 3;
        int i0 = (2 * y3) * 16 + 2 * x3;
        float p3v = 0.25f * ((sp2[i0] + sp2[i0 + 1]) + (sp2[i0 + 16] + sp2[i0 + 17]));
        float t3v = 0.25f * ((st2[i0] + st2[i0 + 1]) + (st2[i0 + 16] + st2[i0 + 17]));
        size_t o3 = ((size_t)ch * 128 + by * 8 + y3) * 128 + bx * 8 + x3;
        p3[o3] = p3v;
        t3[o3] = t3v;
        sp3[tid] = p3v;
        st3[tid] = t3v;
    }
    __syncthreads();
    if (tid < 16) {
        int x4 = tid & 3, y4 = tid >> 2;
        int i0 = (2 * y4) * 8 + 2 * x4;
        float p4v = 0.25f * ((sp3[i0] + sp3[i0 + 1]) + (sp3[i0 + 8] + sp3[i0 + 9]));
        float t4v = 0.25f * ((st3[i0] + st3[i0 + 1]) + (st3[i0 + 8] + st3[i0 + 9]));
        size_t o4 = ((size_t)ch * 64 + by * 4 + y4) * 64 + bx * 4 + x4;
        p4[o4] = p4v;
        t4[o4] = t4v;
    }
}

// Column-strip streaming SSIM, 4-channel ring (p, t, p^2+t^2, p*t).
// B=16 row batches -> ring = 2*16+10 = 42 slots = 22.2 KB LDS -> 7 blocks/CU
// (87% occupancy vs 50% at the old 40 KB ring; all 1740 blocks co-resident).
// Wave-specialized: tid<128 = S2 consumers (4 outputs/thread, 14 ds_read_b128),
// tid>=128 = S1 producers (4-col segs from 14 inputs; load batch i+1 after
// storing batch i -> global latency spans the barrier + next consumer phase).
// Producer lanes are row-major in the low 3 bits: ds_write rows stride 528 B
// = 4 banks apart -> 8 rows cover all 32 banks, conflict-free stores.
__global__ __launch_bounds__(256, 7) void ssim_strip(Ptrs ptrs,
                                                     float* __restrict__ acc) {
    __shared__ v4f hq[RSZ];  // 22176 B
    __shared__ float red[8];

    const int bxi = blockIdx.x;  // 0..173
    int lvl, base;
    if (bxi < 128)      { lvl = 0; base = 0; }
    else if (bxi < 160) { lvl = 1; base = 128; }
    else if (bxi < 168) { lvl = 2; base = 160; }
    else if (bxi < 172) { lvl = 3; base = 168; }
    else                { lvl = 4; base = 172; }
    const int local = bxi - base;
    const int H = 1024 >> lvl;
    const int Wout = H - HALO;
    const int ncol = 32 >> lvl;
    const int cs = local & (ncol - 1);
    const int rsi = local >> (5 - lvl);
    const int X0 = cs * 32;
    const int strip_y0 = rsi * 256;
    const int strip_rows = min(256, Wout - strip_y0);
    const int rows_needed = strip_rows + HALO;
    const int nIter = (strip_rows + 15) >> 4;  // 16 output rows per iter

    const int c = blockIdx.y;
    const float* Pc = ptrs.p[lvl] + (size_t)c * H * H;
    const float* Tc = ptrs.t[lvl] + (size_t)c * H * H;
    const int tid = threadIdx.x;

    // load 14 cols of row gy at col base gxb (gxb is 16B-aligned)
    auto load_row14 = [&](int gy, int gxb, float lp[14], float lt[14]) {
        const float* Pr = Pc + (size_t)gy * H + gxb;
        const float* Tr = Tc + (size_t)gy * H + gxb;
        if (gxb + 14 <= H) {
            float4 a0 = *(const float4*)(Pr);
            float4 a1 = *(const float4*)(Pr + 4);
            float4 a2 = *(const float4*)(Pr + 8);
            float2 a3 = *(const float2*)(Pr + 12);
            lp[0] = a0.x; lp[1] = a0.y; lp[2]  = a0.z; lp[3]  = a0.w;
            lp[4] = a1.x; lp[5] = a1.y; lp[6]  = a1.z; lp[7]  = a1.w;
            lp[8] = a2.x; lp[9] = a2.y; lp[10] = a2.z; lp[11] = a2.w;
            lp[12] = a3.x; lp[13] = a3.y;
            float4 b0 = *(const float4*)(Tr);
            float4 b1 = *(const float4*)(Tr + 4);
            float4 b2 = *(const float4*)(Tr + 8);
            float2 b3 = *(const float2*)(Tr + 12);
            lt[0] = b0.x; lt[1] = b0.y; lt[2]  = b0.z; lt[3]  = b0.w;
            lt[4] = b1.x; lt[5] = b1.y; lt[6]  = b1.z; lt[7]  = b1.w;
            lt[8] = b2.x; lt[9] = b2.y; lt[10] = b2.z; lt[11] = b2.y;
            lt[11] = b2.w;
            lt[12] = b3.x; lt[13] = b3.y;
        } else {
#pragma unroll
            for (int j = 0; j < 14; ++j) {
                float pv = 0.f, tv = 0.f;
                if (gxb + j < H) { pv = Pr[j]; tv = Tr[j]; }
                lp[j] = pv;
                lt[j] = tv;
            }
        }
    };

    // horizontal conv: 4 outputs (cols x0..x0+3) from 14 inputs -> ring slot rr
    auto conv_store4 = [&](int rr, int x0, const float lp[14], const float lt[14]) {
        v4f aq[4] = {};
#pragma unroll
        for (int xi = 0; xi < 14; ++xi) {
            float pv = lp[xi];
            float tv = lt[xi];
            v4f xq = (v4f){pv, tv, pv * pv + tv * tv, pv * tv};
#pragma unroll
            for (int o = 0; o < 4; ++o) {
                int k = xi - o;
                if (k >= 0 && k <= 10) aq[o] = aq[o] + Gc[k] * xq;  // 2x pk_fma
            }
        }
        const int sb = rr * HPITCH + x0;
#pragma unroll
        for (int o = 0; o < 4; ++o) hq[sb + o] = aq[o];  // ds_write_b128
    };

    // ---- Prologue: h-rows 0..25 via 26 rows x 8 segs (208 threads) ----
    {
        const int r = tid >> 3, seg = tid & 7;
        if (r < 26) {
            float lp[14], lt[14];
            load_row14(strip_y0 + r, X0 + 4 * seg, lp, lt);
            conv_store4(r, 4 * seg, lp, lt);
        }
    }

    // ---- Producer preload of batch 0 (rows 26..41) ----
    const bool isProd = (tid >= 128);
    const int idx = tid & 127;
    const int prow = (idx & 7) | ((idx >> 6) << 3);  // rows in low lane bits
    const int pseg = (idx >> 3) & 7;                 // 4-col segment
    float plp[14], plt[14];
    int prRow = 26 + prow;  // absolute h-row of current loaded batch
    int prSlot = prRow;     // ring slot (26+prow < 42)
    bool pHave = false;
    if (isProd && nIter > 1 && prRow < rows_needed) {
        load_row14(strip_y0 + prRow, X0 + 4 * pseg, plp, plt);
        pHave = true;
    }
    __syncthreads();

    // ---- Main loop: 16 output rows/iter, 1 barrier/iter ----
    float cs_sum = 0.f, sim_sum = 0.f;
    const int txl = tid & 31;
    const int g = (tid >> 5) & 3;  // consumer band (tid<128): rows 4g..4g+3
    int y0m = 0;                   // (16*i) % RS
    for (int i = 0; i < nIter; ++i) {
        if (isProd) {
            // store batch i (loaded last iter), then issue batch i+1 loads
            if (pHave) conv_store4(prSlot, 4 * pseg, plp, plt);
            prSlot += 16;
            if (prSlot >= RS) prSlot -= RS;
            prRow += 16;
            pHave = (prRow < rows_needed) && (i + 2 < nIter);
            if (pHave) load_row14(strip_y0 + prRow, X0 + 4 * pseg, plp, plt);
        } else {
            // S2: 4 outputs over 14 resident ring rows
            int sl = y0m + 4 * g;
            if (sl >= RS) sl -= RS;
            int ad = sl * HPITCH + txl;
            v4f a[4] = {};
#pragma unroll
            for (int j = 0; j < 14; ++j) {
                v4f vq = hq[ad];  // ds_read_b128
#pragma unroll
                for (int o = 0; o < 4; ++o) {
                    int k = j - o;
                    if (k >= 0 && k <= 10) a[o] = a[o] + Gc[k] * vq;  // 2x pk_fma
                }
                ad += HPITCH;
                ++sl;
                if (sl >= RS) { sl = 0; ad -= RSZ; }
            }
            const float C1c = 1.0e-4f, C2c = 9.0e-4f;
            const bool colok = (X0 + txl) < Wout;
            const int orow0 = 16 * i + 4 * g;
#pragma unroll
            for (int o = 0; o < 4; ++o) {
                if (colok && (orow0 + o) < strip_rows) {
                    float mu1 = a[o].x, mu2 = a[o].y;
                    float mu1s = mu1 * mu1, mu2s = mu2 * mu2, mu12 = mu1 * mu2;
                    float v2 = a[o].z - mu1s - mu2s + C2c;
                    float v1 = 2.f * (a[o].w - mu12) + C2c;
                    float den2 = mu1s + mu2s + C1c;
                    float num2 = 2.f * mu12 + C1c;
                    float inv = 1.f / (v2 * den2);
                    cs_sum = fmaf(v1 * den2, inv, cs_sum);
                    sim_sum = fmaf(num2 * v1, inv, sim_sum);
                }
            }
        }
        y0m += 16;
        if (y0m >= RS) y0m -= RS;
        __syncthreads();
    }

    // ---- Block reduction (producers contribute zeros) ----
#pragma unroll
    for (int off = 32; off > 0; off >>= 1) {
        cs_sum += __shfl_down(cs_sum, off, 64);
        sim_sum += __shfl_down(sim_sum, off, 64);
    }
    int wave = tid >> 6;
    if ((tid & 63) == 0) {
        red[wave * 2 + 0] = sim_sum;
        red[wave * 2 + 1] = cs_sum;
    }
    __syncthreads();
    if (tid == 0) {
        float s = red[0] + red[2] + red[4] + red[6];
        float cc = red[1] + red[3] + red[5] + red[7];
        atomicAdd(&acc[(lvl * NCH + c) * 2 + 0], s);
        atomicAdd(&acc[(lvl * NCH + c) * 2 + 1], cc);
    }
}

__global__ void finalize_k(const float* __restrict__ acc, float* __restrict__ out) {
    if (threadIdx.x != 0) return;
    const double w[5] = {0.0448, 0.2856, 0.3001, 0.2363, 0.1333};
    const double counts[5] = {1014.0 * 1014.0, 502.0 * 502.0, 246.0 * 246.0,
                              118.0 * 118.0, 54.0 * 54.0};
    double total = 0.0;
    for (int c = 0; c < NCH; ++c) {
        double pc = 1.0;
        for (int l = 0; l < 4; ++l) {
            double mcs = (double)acc[(l * NCH + c) * 2 + 1] / counts[l];
            pc *= pow(mcs, w[l]);
        }
        double ms4 = (double)acc[(4 * NCH + c) * 2 + 0] / counts[4];
        double p2 = pow(ms4, w[4]);
        pc *= (p2 * p2) * (p2 * p2);  // pow2[-1] appears in all 4 product terms
        total += pc;
    }
    *out = (float)(1.0 - total);
}

extern "C" void kernel_launch(void* const* d_in, const int* in_sizes, int n_in,
                              void* d_out, int out_size, void* d_ws, size_t ws_size,
                              hipStream_t stream) {
    const float* P0 = (const float*)d_in[0];
    const float* T0 = (const float*)d_in[1];
    float* out = (float*)d_out;
    float* acc = (float*)d_ws;  // 100 used, 128 reserved

    const size_t n1 = (size_t)NCH * 512 * 512;
    const size_t n2 = (size_t)NCH * 256 * 256;
    const size_t n3 = (size_t)NCH * 128 * 128;
    const size_t n4 = (size_t)NCH * 64 * 64;
    float* p1 = acc + 128;
    float* t1 = p1 + n1;
    float* p2 = t1 + n1;
    float* t2 = p2 + n2;
    float* p3 = t2 + n2;
    float* t3 = p3 + n3;
    float* p4 = t3 + n3;
    float* t4 = p4 + n4;

    pool_all<<<2560, 256, 0, stream>>>(P0, T0, p1, t1, p2, t2, p3, t3, p4, t4, acc);

    Ptrs ptrs;
    ptrs.p[0] = P0; ptrs.t[0] = T0;
    ptrs.p[1] = p1; ptrs.t[1] = t1;
    ptrs.p[2] = p2; ptrs.t[2] = t2;
    ptrs.p[3] = p3; ptrs.t[3] = t3;
    ptrs.p[4] = p4; ptrs.t[4] = t4;

    ssim_strip<<<dim3(174, NCH, 1), 256, 0, stream>>>(ptrs, acc);

    finalize_k<<<1, 64, 0, stream>>>(acc, out);
}

// Round 2
// 206.624 us; speedup vs baseline: 1.8856x; 1.8856x over previous
//
#include <hip/hip_runtime.h>
#include <cstddef>

#define WIN 11
#define HALO 10
#define NCH 10

typedef float v4f __attribute__((ext_vector_type(4)));

// Normalized 1D Gaussian, sigma=1.5 (constexpr: unrolled taps fold to immediates)
constexpr float Gc[WIN] = {
    0.00102838f, 0.00759876f, 0.03600077f, 0.10936069f, 0.21300554f,
    0.26601173f, 0.21300554f, 0.10936069f, 0.03600077f, 0.00759876f,
    0.00102838f};

constexpr int HPITCH = 33;        // odd pitch: spread banks
constexpr int RS = 42;            // ring slots; B=16 batch: live span 2*16+10 = 42
constexpr int RSZ = RS * HPITCH;  // 1386 v4f = 22176 B -> 7 blocks/CU (LDS-limited)

struct Ptrs {
    const float* p[5];
    const float* t[5];
};

// ---- One-shot pyramid: 64x64 lvl0 tile -> lvl1..4, plus acc zeroing ----
// (~110 MB in ~15us ~= 7 TB/s: at the HBM/L3 roofline — do not touch)
__global__ __launch_bounds__(256) void pool_all(
    const float* __restrict__ P0, const float* __restrict__ T0,
    float* __restrict__ p1, float* __restrict__ t1,
    float* __restrict__ p2, float* __restrict__ t2,
    float* __restrict__ p3, float* __restrict__ t3,
    float* __restrict__ p4, float* __restrict__ t4,
    float* __restrict__ acc) {
    __shared__ float sp2[256], st2[256], sp3[64], st3[64];
    const int tid = threadIdx.x;
    if (blockIdx.x == 0 && tid < 128) acc[tid] = 0.f;

    const int b = blockIdx.x;  // 2560 = 10ch x 16 x 16
    const int bx = b & 15, by = (b >> 4) & 15, ch = b >> 8;
    const int tx = tid & 15, ty = tid >> 4;

    const size_t rbase =
        ((size_t)ch * 1024 + by * 64 + ty * 4) * 1024 + bx * 64 + tx * 4;
    float4 pr[4], tr[4];
#pragma unroll
    for (int r2 = 0; r2 < 4; ++r2) {
        pr[r2] = *(const float4*)(P0 + rbase + (size_t)r2 * 1024);
        tr[r2] = *(const float4*)(T0 + rbase + (size_t)r2 * 1024);
    }
    float p1a = 0.25f * ((pr[0].x + pr[0].y) + (pr[1].x + pr[1].y));
    float p1b = 0.25f * ((pr[0].z + pr[0].w) + (pr[1].z + pr[1].w));
    float p1c = 0.25f * ((pr[2].x + pr[2].y) + (pr[3].x + pr[3].y));
    float p1d = 0.25f * ((pr[2].z + pr[2].w) + (pr[3].z + pr[3].w));
    float t1a = 0.25f * ((tr[0].x + tr[0].y) + (tr[1].x + tr[1].y));
    float t1b = 0.25f * ((tr[0].z + tr[0].w) + (tr[1].z + tr[1].w));
    float t1c = 0.25f * ((tr[2].x + tr[2].y) + (tr[3].x + tr[3].y));
    float t1d = 0.25f * ((tr[2].z + tr[2].w) + (tr[3].z + tr[3].w));
    size_t o1 = ((size_t)ch * 512 + by * 32 + ty * 2) * 512 + bx * 32 + tx * 2;
    *(float2*)(p1 + o1) = make_float2(p1a, p1b);
    *(float2*)(p1 + o1 + 512) = make_float2(p1c, p1d);
    *(float2*)(t1 + o1) = make_float2(t1a, t1b);
    *(float2*)(t1 + o1 + 512) = make_float2(t1c, t1d);
    float p2v = 0.25f * ((p1a + p1b) + (p1c + p1d));
    float t2v = 0.25f * ((t1a + t1b) + (t1c + t1d));
    size_t o2 = ((size_t)ch * 256 + by * 16 + ty) * 256 + bx * 16 + tx;
    p2[o2] = p2v;
    t2[o2] = t2v;
    sp2[tid] = p2v;
    st2[tid] = t2v;
    __syncthreads();
    if (tid < 64) {
        int x3 = tid & 7, y3 = tid >> 3;
        int i0 = (2 * y3) * 16 + 2 * x3;
        float p3v = 0.25f * ((sp2[i0] + sp2[i0 + 1]) + (sp2[i0 + 16] + sp2[i0 + 17]));
        float t3v = 0.25f * ((st2[i0] + st2[i0 + 1]) + (st2[i0 + 16] + st2[i0 + 17]));
        size_t o3 = ((size_t)ch * 128 + by * 8 + y3) * 128 + bx * 8 + x3;
        p3[o3] = p3v;
        t3[o3] = t3v;
        sp3[tid] = p3v;
        st3[tid] = t3v;
    }
    __syncthreads();
    if (tid < 16) {
        int x4 = tid & 3, y4 = tid >> 2;
        int i0 = (2 * y4) * 8 + 2 * x4;
        float p4v = 0.25f * ((sp3[i0] + sp3[i0 + 1]) + (sp3[i0 + 8] + sp3[i0 + 9]));
        float t4v = 0.25f * ((st3[i0] + st3[i0 + 1]) + (st3[i0 + 8] + st3[i0 + 9]));
        size_t o4 = ((size_t)ch * 64 + by * 4 + y4) * 64 + bx * 4 + x4;
        p4[o4] = p4v;
        t4[o4] = t4v;
    }
}

// 14 floats held as NAMED vector registers (never indexable -> can't be
// demoted to scratch; R1's float[14] lambda-param arrays spilled 484 MB).
struct V14 {
    float4 a, b, c;
    float2 d;
};

__device__ __forceinline__ float v14el(const V14& v, int j) {
    // j is compile-time after unrolling: folds to a register reference
    switch (j) {
        case 0:  return v.a.x;
        case 1:  return v.a.y;
        case 2:  return v.a.z;
        case 3:  return v.a.w;
        case 4:  return v.b.x;
        case 5:  return v.b.y;
        case 6:  return v.b.z;
        case 7:  return v.b.w;
        case 8:  return v.c.x;
        case 9:  return v.c.y;
        case 10: return v.c.z;
        case 11: return v.c.w;
        case 12: return v.d.x;
        default: return v.d.y;
    }
}

__device__ __forceinline__ void loadV14(const float* R, int rem, V14& v) {
    if (rem >= 14) {  // interior: 3x dwordx4 + 1x dwordx2, 16B-aligned
        v.a = *(const float4*)R;
        v.b = *(const float4*)(R + 4);
        v.c = *(const float4*)(R + 8);
        v.d = *(const float2*)(R + 12);
    } else {  // right edge of last column strip: guarded scalars, zero-pad
        v.a.x = (rem > 0) ? R[0] : 0.f;
        v.a.y = (rem > 1) ? R[1] : 0.f;
        v.a.z = (rem > 2) ? R[2] : 0.f;
        v.a.w = (rem > 3) ? R[3] : 0.f;
        v.b.x = (rem > 4) ? R[4] : 0.f;
        v.b.y = (rem > 5) ? R[5] : 0.f;
        v.b.z = (rem > 6) ? R[6] : 0.f;
        v.b.w = (rem > 7) ? R[7] : 0.f;
        v.c.x = (rem > 8) ? R[8] : 0.f;
        v.c.y = (rem > 9) ? R[9] : 0.f;
        v.c.z = (rem > 10) ? R[10] : 0.f;
        v.c.w = (rem > 11) ? R[11] : 0.f;
        v.d.x = (rem > 12) ? R[12] : 0.f;
        v.d.y = 0.f;
    }
}

// 2 h-conv outputs (cols jbase..jbase+1) from inputs jbase..jbase+11.
// Two 2-col passes instead of one 4-col pass: only 8 accumulator VGPRs live
// against the 28 data VGPRs (same 44 taps total; +10 cheap xq rebuilds).
__device__ __forceinline__ void conv2(const V14& p, const V14& t, int jbase,
                                      v4f& o0, v4f& o1) {
    v4f a0 = (v4f){0.f, 0.f, 0.f, 0.f};
    v4f a1 = a0;
#pragma unroll
    for (int u = 0; u < 12; ++u) {
        float pv = v14el(p, jbase + u);
        float tv = v14el(t, jbase + u);
        v4f xq = (v4f){pv, tv, pv * pv + tv * tv, pv * tv};
        if (u <= 10) a0 += Gc[u] * xq;      // 2x pk_fma
        if (u >= 1)  a1 += Gc[u - 1] * xq;  // 2x pk_fma
    }
    o0 = a0;
    o1 = a1;
}

__device__ __forceinline__ void conv_store4(v4f* __restrict__ hq, int rr, int x0,
                                            const V14& p, const V14& t) {
    const int sb = rr * HPITCH + x0;
    v4f o0, o1;
    conv2(p, t, 0, o0, o1);
    hq[sb + 0] = o0;  // ds_write_b128
    hq[sb + 1] = o1;
    conv2(p, t, 2, o0, o1);
    hq[sb + 2] = o0;
    hq[sb + 3] = o1;
}

// Column-strip streaming SSIM, 4-channel ring (p, t, p^2+t^2, p*t).
// B=16 row batches -> ring = 2*16+10 = 42 slots = 22.2 KB LDS -> 7 blocks/CU;
// all 1740 blocks co-resident. launch_bounds(256,8) pins VGPR<=64 (the HW
// occupancy step: waves halve at 64/128/256) — state is all named vector regs
// so the R1 scratch-demotion cannot recur.
// Wave-specialized: tid<128 = v-conv consumers (4 outputs/thread, 14
// ds_read_b128), tid>=128 = h-conv producers (4-col segs from 14 inputs;
// store batch i then issue batch i+1 loads -> latency spans the barrier).
// Producer lanes row-major in low 3 bits: row stride 528 B = 4 banks -> 8
// rows cover all 32 banks, conflict-free ds_write.
__global__ __launch_bounds__(256, 8) void ssim_strip(Ptrs ptrs,
                                                     float* __restrict__ acc) {
    __shared__ v4f hq[RSZ];  // 22176 B
    __shared__ float red[8];

    const int bxi = blockIdx.x;  // 0..173
    int lvl, base;
    if (bxi < 128)      { lvl = 0; base = 0; }
    else if (bxi < 160) { lvl = 1; base = 128; }
    else if (bxi < 168) { lvl = 2; base = 160; }
    else if (bxi < 172) { lvl = 3; base = 168; }
    else                { lvl = 4; base = 172; }
    const int local = bxi - base;
    const int H = 1024 >> lvl;
    const int Wout = H - HALO;
    const int ncol = 32 >> lvl;
    const int cs = local & (ncol - 1);
    const int rsi = local >> (5 - lvl);
    const int X0 = cs * 32;
    const int strip_y0 = rsi * 256;
    const int strip_rows = min(256, Wout - strip_y0);
    const int rows_needed = strip_rows + HALO;  // >= 64 for all strips
    const int nIter = (strip_rows + 15) >> 4;   // 16 output rows/iter, >= 4

    const int c = blockIdx.y;
    const float* Pc = ptrs.p[lvl] + (size_t)c * H * H;
    const float* Tc = ptrs.t[lvl] + (size_t)c * H * H;
    const int tid = threadIdx.x;

    // ---- Prologue: h-rows 0..25 via 26 rows x 8 segs (208 threads) ----
    {
        const int r = tid >> 3, seg = tid & 7;
        if (r < 26) {
            const int gxb = X0 + 4 * seg;
            const int rem = H - gxb;
            const size_t ro = (size_t)(strip_y0 + r) * H + gxb;
            V14 p, t;
            loadV14(Pc + ro, rem, p);
            loadV14(Tc + ro, rem, t);
            conv_store4(hq, r, 4 * seg, p, t);
        }
    }

    // ---- Producer setup + preload of batch 0 (h-rows 26..41) ----
    const bool isProd = (tid >= 128);
    const int idx = tid & 127;
    const int prow = (idx & 7) | ((idx >> 6) << 3);  // rows in low lane bits
    const int pseg = (idx >> 3) & 7;                 // 4-col segment
    const int pgxb = X0 + 4 * pseg;
    const int prem = H - pgxb;
    const float* Pp = Pc + (size_t)(strip_y0 + 26 + prow) * H + pgxb;
    const float* Tp = Tc + (size_t)(strip_y0 + 26 + prow) * H + pgxb;
    V14 pp, pt;            // persistent producer state: exactly 28 VGPRs
    int prSlot = 26 + prow;  // ring slot of loaded batch (< 42)
    int prRowRel = 26 + prow;
    bool pHave = false;
    if (isProd) {  // 26+prow <= 41 < rows_needed always
        loadV14(Pp, prem, pp);
        loadV14(Tp, prem, pt);
        pHave = true;
    }
    __syncthreads();

    // ---- Main loop: 16 output rows/iter, 1 barrier/iter ----
    float cs_sum = 0.f, sim_sum = 0.f;
    const int txl = tid & 31;
    const int g = (tid >> 5) & 3;  // consumer band (tid<128): rows 4g..4g+3
    int y0m = 0;                   // (16*i) % RS
    for (int i = 0; i < nIter; ++i) {
        if (isProd) {
            // store batch i (loaded last iter), then issue batch i+1 loads
            if (pHave) conv_store4(hq, prSlot, 4 * pseg, pp, pt);
            prSlot += 16;
            if (prSlot >= RS) prSlot -= RS;
            prRowRel += 16;
            Pp += (size_t)16 * H;
            Tp += (size_t)16 * H;
            pHave = (prRowRel < rows_needed) && (i + 2 < nIter);
            if (pHave) {
                loadV14(Pp, prem, pp);
                loadV14(Tp, prem, pt);
            }
        } else {
            // v-conv: 4 outputs over 14 resident ring rows
            int sl = y0m + 4 * g;
            if (sl >= RS) sl -= RS;
            int ad = sl * HPITCH + txl;
            v4f a0 = (v4f){0.f, 0.f, 0.f, 0.f};
            v4f a1 = a0, a2 = a0, a3 = a0;
#pragma unroll
            for (int j = 0; j < 14; ++j) {
                v4f vq = hq[ad];  // ds_read_b128
                if (j <= 10)           a0 += Gc[j] * vq;
                if (j >= 1 && j <= 11) a1 += Gc[j - 1] * vq;
                if (j >= 2 && j <= 12) a2 += Gc[j - 2] * vq;
                if (j >= 3)            a3 += Gc[j - 3] * vq;
                ad += HPITCH;
                ++sl;
                if (sl >= RS) { sl = 0; ad -= RSZ; }
            }
            const float C1c = 1.0e-4f, C2c = 9.0e-4f;
            const bool colok = (X0 + txl) < Wout;
            const int orow0 = 16 * i + 4 * g;
            auto emit = [&](const v4f& av, int o) {
                if (colok && (orow0 + o) < strip_rows) {
                    float mu1 = av.x, mu2 = av.y;
                    float mu1s = mu1 * mu1, mu2s = mu2 * mu2, mu12 = mu1 * mu2;
                    float v2 = av.z - mu1s - mu2s + C2c;
                    float v1 = 2.f * (av.w - mu12) + C2c;
                    float den2 = mu1s + mu2s + C1c;
                    float num2 = 2.f * mu12 + C1c;
                    float inv = 1.f / (v2 * den2);
                    cs_sum = fmaf(v1 * den2, inv, cs_sum);
                    sim_sum = fmaf(num2 * v1, inv, sim_sum);
                }
            };
            emit(a0, 0);
            emit(a1, 1);
            emit(a2, 2);
            emit(a3, 3);
        }
        y0m += 16;
        if (y0m >= RS) y0m -= RS;
        __syncthreads();
    }

    // ---- Block reduction (producers contribute zeros) ----
#pragma unroll
    for (int off = 32; off > 0; off >>= 1) {
        cs_sum += __shfl_down(cs_sum, off, 64);
        sim_sum += __shfl_down(sim_sum, off, 64);
    }
    int wave = tid >> 6;
    if ((tid & 63) == 0) {
        red[wave * 2 + 0] = sim_sum;
        red[wave * 2 + 1] = cs_sum;
    }
    __syncthreads();
    if (tid == 0) {
        float s = red[0] + red[2] + red[4] + red[6];
        float cc = red[1] + red[3] + red[5] + red[7];
        atomicAdd(&acc[(lvl * NCH + c) * 2 + 0], s);
        atomicAdd(&acc[(lvl * NCH + c) * 2 + 1], cc);
    }
}

__global__ void finalize_k(const float* __restrict__ acc, float* __restrict__ out) {
    if (threadIdx.x != 0) return;
    const double w[5] = {0.0448, 0.2856, 0.3001, 0.2363, 0.1333};
    const double counts[5] = {1014.0 * 1014.0, 502.0 * 502.0, 246.0 * 246.0,
                              118.0 * 118.0, 54.0 * 54.0};
    double total = 0.0;
    for (int c = 0; c < NCH; ++c) {
        double pc = 1.0;
        for (int l = 0; l < 4; ++l) {
            double mcs = (double)acc[(l * NCH + c) * 2 + 1] / counts[l];
            pc *= pow(mcs, w[l]);
        }
        double ms4 = (double)acc[(4 * NCH + c) * 2 + 0] / counts[4];
        double p2 = pow(ms4, w[4]);
        pc *= (p2 * p2) * (p2 * p2);  // pow2[-1] appears in all 4 product terms
        total += pc;
    }
    *out = (float)(1.0 - total);
}

extern "C" void kernel_launch(void* const* d_in, const int* in_sizes, int n_in,
                              void* d_out, int out_size, void* d_ws, size_t ws_size,
                              hipStream_t stream) {
    const float* P0 = (const float*)d_in[0];
    const float* T0 = (const float*)d_in[1];
    float* out = (float*)d_out;
    float* acc = (float*)d_ws;  // 100 used, 128 reserved

    const size_t n1 = (size_t)NCH * 512 * 512;
    const size_t n2 = (size_t)NCH * 256 * 256;
    const size_t n3 = (size_t)NCH * 128 * 128;
    const size_t n4 = (size_t)NCH * 64 * 64;
    float* p1 = acc + 128;
    float* t1 = p1 + n1;
    float* p2 = t1 + n1;
    float* t2 = p2 + n2;
    float* p3 = t2 + n2;
    float* t3 = p3 + n3;
    float* p4 = t3 + n3;
    float* t4 = p4 + n4;

    pool_all<<<2560, 256, 0, stream>>>(P0, T0, p1, t1, p2, t2, p3, t3, p4, t4, acc);

    Ptrs ptrs;
    ptrs.p[0] = P0; ptrs.t[0] = T0;
    ptrs.p[1] = p1; ptrs.t[1] = t1;
    ptrs.p[2] = p2; ptrs.t[2] = t2;
    ptrs.p[3] = p3; ptrs.t[3] = t3;
    ptrs.p[4] = p4; ptrs.t[4] = t4;

    ssim_strip<<<dim3(174, NCH, 1), 256, 0, stream>>>(ptrs, acc);

    finalize_k<<<1, 64, 0, stream>>>(acc, out);
}